// Round 2
// baseline (751.056 us; speedup 1.0000x reference)
//
#include <hip/hip_runtime.h>
#include <stdint.h>

#define NNODES (1024*256)      // 262144
#define NEDGES (2*NNODES)      // 524288
#define H 128
#define LAYERS 4

typedef unsigned int uint;
typedef unsigned short ushort;

typedef short short8 __attribute__((ext_vector_type(8)));
typedef float f32x4 __attribute__((ext_vector_type(4)));

__device__ __forceinline__ ushort f2bf(float f){
  uint u = __float_as_uint(f);
  u = (u + 0x7FFFu + ((u>>16)&1u)) >> 16;
  return (ushort)u;
}
__device__ __forceinline__ float bf2f(ushort b){
  return __uint_as_float(((uint)b)<<16);
}

// ---------------- degree / norm precompute ----------------
__global__ void deg_k(const int* __restrict__ ei, int* __restrict__ deg){
  int e = blockIdx.x*256 + threadIdx.x;
  atomicAdd(&deg[ei[NEDGES + e]], 1);   // dst row of edge_index
}

__global__ void dis_k(const int* __restrict__ deg, float* __restrict__ dis){
  int v = blockIdx.x*256 + threadIdx.x;
  dis[v] = rsqrtf((float)(deg[v] + 1));  // +1 self loop; always >0
}

// ---------------- CSR build: exclusive scan of in-degree ----------------
__global__ void scan1_k(const int* __restrict__ deg, int* __restrict__ rp, int* __restrict__ bsum){
  __shared__ int lds[256];
  int b = blockIdx.x, t = threadIdx.x;
  int base = b*1024 + t*4;
  int4 d = *(const int4*)(deg + base);
  int s = d.x + d.y + d.z + d.w;
  lds[t] = s; __syncthreads();
  for (int off=1; off<256; off<<=1){
    int o = (t>=off) ? lds[t-off] : 0;
    __syncthreads();
    lds[t] += o;
    __syncthreads();
  }
  int incl = lds[t];
  int excl = incl - s;
  if (t==255) bsum[b] = incl;
  int p = excl;
  rp[base+0]=p; p+=d.x; rp[base+1]=p; p+=d.y; rp[base+2]=p; p+=d.z; rp[base+3]=p;
}

__global__ void scan2_k(int* __restrict__ bsum){
  __shared__ int lds[256];
  int t = threadIdx.x;
  int s = bsum[t];
  lds[t] = s; __syncthreads();
  for (int off=1; off<256; off<<=1){
    int o = (t>=off) ? lds[t-off] : 0;
    __syncthreads();
    lds[t] += o;
    __syncthreads();
  }
  bsum[t] = lds[t] - s;  // exclusive block offsets
}

__global__ void scan3_k(int* __restrict__ rp, const int* __restrict__ bsum, int* __restrict__ cur){
  int i = blockIdx.x*256 + threadIdx.x;
  int val = rp[i] + bsum[i>>10];
  rp[i] = val;
  cur[i] = val;
  if (i==0) rp[NNODES] = NEDGES;
}

__global__ void fill_k(const int* __restrict__ ei, const float* __restrict__ dis,
                       int* __restrict__ cur, int* __restrict__ esrc, float* __restrict__ ewn){
  int e = blockIdx.x*256 + threadIdx.x;
  int s = ei[e];
  int d = ei[NEDGES + e];
  int pos = atomicAdd(&cur[d], 1);
  esrc[pos] = s;
  ewn[pos]  = dis[s]*dis[d];
}

// ---------------- W transpose + bf16 convert ----------------
__global__ void wconv_k(const float* __restrict__ Ws, ushort* __restrict__ Wt){
  int gid = blockIdx.x*256 + threadIdx.x;     // 4*128*128 = 65536
  int l = gid>>14, rem = gid&16383, c = rem>>7, k = rem&127;
  Wt[(size_t)l*16384 + c*H + k] = f2bf(Ws[(size_t)l*16384 + k*H + c]);
}

// ---------------- node embedding ----------------
__global__ void embed_k(const int* __restrict__ x, const float* __restrict__ ce,
                        const float* __restrict__ ne, float* __restrict__ h){
  int gid = blockIdx.x*256 + threadIdx.x;     // NNODES*32
  int v = gid>>5, q = gid&31;
  int x0 = x[2*v], x1 = x[2*v+1];
  float4 a = *(const float4*)(ce + (size_t)x0*H + q*4);
  float4 b = *(const float4*)(ne + (size_t)x1*H + q*4);
  float4 r; r.x=a.x+b.x; r.y=a.y+b.y; r.z=a.z+b.z; r.w=a.w+b.w;
  *(float4*)(h + (size_t)v*H + q*4) = r;
}

// ---------------- GEMM: hw[N,128] = bf16(h) @ W (bf16 MFMA, W in regs) ----------------
__global__ __launch_bounds__(256,2) void gemm_k(
    const float* __restrict__ h, const ushort* __restrict__ Wt, ushort* __restrict__ hw)
{
  const int wave = threadIdx.x>>6;
  const int lane = threadIdx.x&63;
  const int lr = lane&15;       // A row / B col within tile
  const int lg = lane>>4;       // k-group

  short8 Bf[8][4];
#pragma unroll
  for (int ct=0; ct<8; ct++)
#pragma unroll
    for (int kk=0; kk<4; kk++)
      Bf[ct][kk] = *(const short8*)(Wt + (size_t)(ct*16+lr)*H + kk*32 + lg*8);

  for (int tile = blockIdx.x; tile < NNODES/64; tile += gridDim.x){
    const float* hr = h + ((size_t)(tile*64 + wave*16 + lr))*H;
    short8 Af[4];
#pragma unroll
    for (int kk=0; kk<4; kk++){
      const float4 f0 = *(const float4*)(hr + kk*32 + lg*8);
      const float4 f1 = *(const float4*)(hr + kk*32 + lg*8 + 4);
      short8 a;
      a[0]=(short)f2bf(f0.x); a[1]=(short)f2bf(f0.y); a[2]=(short)f2bf(f0.z); a[3]=(short)f2bf(f0.w);
      a[4]=(short)f2bf(f1.x); a[5]=(short)f2bf(f1.y); a[6]=(short)f2bf(f1.z); a[7]=(short)f2bf(f1.w);
      Af[kk]=a;
    }
    f32x4 acc[8];
#pragma unroll
    for (int ct=0; ct<8; ct++){
      f32x4 z = {0.f,0.f,0.f,0.f};
      acc[ct] = z;
#pragma unroll
      for (int kk=0; kk<4; kk++)
        acc[ct] = __builtin_amdgcn_mfma_f32_16x16x32_bf16(Af[kk], Bf[ct][kk], acc[ct], 0, 0, 0);
    }
    // D: row=(lane>>4)*4+i, col=ct*16+(lane&15)  [measured layout]
    ushort* orow = hw + ((size_t)(tile*64 + wave*16 + lg*4))*H;
#pragma unroll
    for (int ct=0; ct<8; ct++)
#pragma unroll
      for (int i=0; i<4; i++)
        orow[(size_t)i*H + ct*16 + lr] = f2bf(acc[ct][i]);
  }
}

// ---------------- fused aggregate + bias + ReLU + residual + LayerNorm ----------------
__global__ __launch_bounds__(256) void agg_ln_k(
  const ushort* __restrict__ hw, float* __restrict__ h,
  const int* __restrict__ rp, const int* __restrict__ esrc,
  const float* __restrict__ ewn, const float* __restrict__ dis,
  const float* __restrict__ bias, const float* __restrict__ lng,
  const float* __restrict__ lnb)
{
  const int lane = threadIdx.x & 63;
  const int v = blockIdx.x*4 + (threadIdx.x>>6);
  const int d0 = lane*2;

  float dv = dis[v];
  uint u = *(const uint*)(hw + (size_t)v*H + d0);     // self loop
  float a0 = dv*dv*bf2f((ushort)u);
  float a1 = dv*dv*bf2f((ushort)(u>>16));

  int beg = rp[v], end = rp[v+1];
  for (int j=beg; j<end; j++){
    int s = esrc[j]; float w = ewn[j];
    uint m = *(const uint*)(hw + (size_t)s*H + d0);
    a0 += w*bf2f((ushort)m);
    a1 += w*bf2f((ushort)(m>>16));
  }
  a0 += bias[d0]; a1 += bias[d0+1];

  float2 hres = *(const float2*)(h + (size_t)v*H + d0);
  float z0 = hres.x + fmaxf(a0, 0.f);
  float z1 = hres.y + fmaxf(a1, 0.f);

  float s1 = z0+z1, s2 = z0*z0+z1*z1;
#pragma unroll
  for (int off=32; off; off>>=1){
    s1 += __shfl_xor(s1, off);
    s2 += __shfl_xor(s2, off);
  }
  float mu  = s1*(1.f/128.f);
  float var = s2*(1.f/128.f) - mu*mu;
  float inv = rsqrtf(var + 1e-5f);
  float y0 = (z0-mu)*inv*lng[d0]   + lnb[d0];
  float y1 = (z1-mu)*inv*lng[d0+1] + lnb[d0+1];
  *(float2*)(h + (size_t)v*H + d0) = make_float2(y0, y1);
}

// ---------------- readout: out[256,32] = h[roots] @ out_w ----------------
__global__ void out_k(const float* __restrict__ h, const float* __restrict__ ow, float* __restrict__ out){
  int gid = blockIdx.x*256 + threadIdx.x;    // 8192
  int t = gid>>5, c = gid&31;
  const float* hr = h + (size_t)t*1024*H;    // root = node 0 of tree t
  float acc = 0.f;
#pragma unroll 8
  for (int k=0; k<H; k++) acc += hr[k]*ow[k*32+c];
  out[gid] = acc;
}

extern "C" void kernel_launch(void* const* d_in, const int* in_sizes, int n_in,
                              void* d_out, int out_size, void* d_ws, size_t ws_size,
                              hipStream_t stream)
{
  const int*   x   = (const int*)d_in[0];
  const int*   ei  = (const int*)d_in[1];
  // d_in[2] = batch (unused; roots are node 0 of each tree)
  const float* ce  = (const float*)d_in[3];
  const float* ne  = (const float*)d_in[4];
  const float* Ws  = (const float*)d_in[5];
  const float* bs  = (const float*)d_in[6];
  const float* lng = (const float*)d_in[7];
  const float* lnb = (const float*)d_in[8];
  const float* ow  = (const float*)d_in[9];
  float* out = (float*)d_out;

  char* p = (char*)d_ws;
  auto alloc = [&](size_t bytes)->char*{ char* r = p; p += (bytes + 255) & ~(size_t)255; return r; };
  float*  h    = (float*) alloc((size_t)NNODES*H*4);
  ushort* hw   = (ushort*)alloc((size_t)NNODES*H*2);
  ushort* Wt   = (ushort*)alloc((size_t)LAYERS*H*H*2);
  int*    deg  = (int*)   alloc((size_t)NNODES*4);
  float*  dis  = (float*) alloc((size_t)NNODES*4);
  int*    rp   = (int*)   alloc((size_t)(NNODES+1)*4);
  int*    cur  = (int*)   alloc((size_t)NNODES*4);
  int*    esrc = (int*)   alloc((size_t)NEDGES*4);
  float*  ewn  = (float*) alloc((size_t)NEDGES*4);
  int*    bsum = (int*)   alloc(256*4);

  hipMemsetAsync(deg, 0, (size_t)NNODES*4, stream);
  deg_k  <<<NEDGES/256, 256, 0, stream>>>(ei, deg);
  dis_k  <<<NNODES/256, 256, 0, stream>>>(deg, dis);
  scan1_k<<<256, 256, 0, stream>>>(deg, rp, bsum);
  scan2_k<<<1, 256, 0, stream>>>(bsum);
  scan3_k<<<NNODES/256, 256, 0, stream>>>(rp, bsum, cur);
  fill_k <<<NEDGES/256, 256, 0, stream>>>(ei, dis, cur, esrc, ewn);
  wconv_k<<<256, 256, 0, stream>>>(Ws, Wt);
  embed_k<<<NNODES*32/256, 256, 0, stream>>>(x, ce, ne, h);

  for (int l=0; l<LAYERS; l++){
    gemm_k  <<<2048, 256, 0, stream>>>(h, Wt + (size_t)l*H*H, hw);
    agg_ln_k<<<NNODES/4, 256, 0, stream>>>(hw, h, rp, esrc, ewn, dis,
                                           bs + (size_t)l*H, lng + (size_t)l*H, lnb + (size_t)l*H);
  }
  out_k<<<32, 256, 0, stream>>>(h, ow, out);
}